// Round 4
// baseline (725.410 us; speedup 1.0000x reference)
//
#include <hip/hip_runtime.h>
#include <math.h>

#define C 96
#define K 512
#define P_PER_B 110592   // 48*48*48
#define NPOS 221184      // 2 * 110592

// ---------------------------------------------------------------------------
// Strategy (validated round 3, absmax=0): harness reference is fp32 numpy.
// Fast FMA pass computes best/second + margin; margin < 3e-4*||x|| positions
// (~1%) are re-resolved with a bit-exact numpy-fp32 emulation.
//
// Round 4 perf fix: round-3 main pass showed VGPR_Count=60 -> the compiler
// REMATERIALIZED the 96-channel x vector instead of keeping it resident,
// re-loading x from L1/L2 inside the 512-prototype loop (VALUBusy 61%,
// 3.7x over FMA-issue floor). volatile loads cannot be duplicated ->
// forces exactly-once load + register residency of all 96 values.
// ---------------------------------------------------------------------------

// Workspace: pn[512][96] fp32, numpy-exact normalized prototypes (192 KB).

__global__ __launch_bounds__(256) void prep_kernel(const float* __restrict__ proto,
                                                   float* __restrict__ pn) {
    int k = blockIdx.x * 256 + threadIdx.x;
    if (k >= K) return;
    const float* row = proto + k * C;
    // numpy pairwise_sum, n=96 <= blocksize: 8 accumulators + fixed combine
    float r[8];
#pragma unroll
    for (int j = 0; j < 8; ++j) r[j] = __fmul_rn(row[j], row[j]);
    for (int i = 8; i < C; i += 8) {
#pragma unroll
        for (int j = 0; j < 8; ++j)
            r[j] = __fadd_rn(r[j], __fmul_rn(row[i + j], row[i + j]));
    }
    float res = __fadd_rn(__fadd_rn(__fadd_rn(r[0], r[1]), __fadd_rn(r[2], r[3])),
                          __fadd_rn(__fadd_rn(r[4], r[5]), __fadd_rn(r[6], r[7])));
    float n = fmaxf(__fsqrt_rn(res), 1e-12f);
    float* dst = pn + k * C;
    for (int c = 0; c < C; ++c) dst[c] = __fdiv_rn(row[c], n);
}

// --- macro machinery: 96 named scalar x registers --------------------------
#define LX(i) const float x##i = xv[(size_t)(i) * P_PER_B];
#define LX8(a,b,c,d,e,f,g,h) LX(a) LX(b) LX(c) LX(d) LX(e) LX(f) LX(g) LX(h)

#define N2(i) n2 = fmaf(x##i, x##i, n2);
#define N28(a,b,c,d,e,f,g,h) N2(a) N2(b) N2(c) N2(d) N2(e) N2(f) N2(g) N2(h)

#define STEP(J, A, B, Cc, D)                  \
    {                                         \
        const float4 q = pr[J];               \
        s0 = fmaf(x##A, q.x, s0);             \
        s1 = fmaf(x##B, q.y, s1);             \
        s2 = fmaf(x##Cc, q.z, s2);            \
        s3 = fmaf(x##D, q.w, s3);             \
    }

__global__ __launch_bounds__(256, 2) void sim_argmax_kernel(
        const float* __restrict__ x,
        const float* __restrict__ pn,
        int* __restrict__ out) {
    int g = blockIdx.x * 256 + threadIdx.x;   // grid exact: g < NPOS
    int b = (g >= P_PER_B) ? 1 : 0;
    int p = g - b * P_PER_B;
    // volatile: loads are not duplicable -> the 96 values MUST stay in VGPRs.
    // Coalesced across lanes (consecutive positions); one-time 85 MB read.
    const volatile float* xv = x + (size_t)b * (size_t)C * P_PER_B + p;

    LX8( 0, 1, 2, 3, 4, 5, 6, 7)  LX8( 8, 9,10,11,12,13,14,15)
    LX8(16,17,18,19,20,21,22,23)  LX8(24,25,26,27,28,29,30,31)
    LX8(32,33,34,35,36,37,38,39)  LX8(40,41,42,43,44,45,46,47)
    LX8(48,49,50,51,52,53,54,55)  LX8(56,57,58,59,60,61,62,63)
    LX8(64,65,66,67,68,69,70,71)  LX8(72,73,74,75,76,77,78,79)
    LX8(80,81,82,83,84,85,86,87)  LX8(88,89,90,91,92,93,94,95)

    float n2 = 0.f;
    N28( 0, 1, 2, 3, 4, 5, 6, 7)  N28( 8, 9,10,11,12,13,14,15)
    N28(16,17,18,19,20,21,22,23)  N28(24,25,26,27,28,29,30,31)
    N28(32,33,34,35,36,37,38,39)  N28(40,41,42,43,44,45,46,47)
    N28(48,49,50,51,52,53,54,55)  N28(56,57,58,59,60,61,62,63)
    N28(64,65,66,67,68,69,70,71)  N28(72,73,74,75,76,77,78,79)
    N28(80,81,82,83,84,85,86,87)  N28(88,89,90,91,92,93,94,95)

    float best = -3.4e38f, second = -3.4e38f;
    int bestk = 0;

#pragma unroll 2
    for (int k = 0; k < K; ++k) {
        const float4* pr = (const float4*)(pn + (size_t)k * C);  // 384 B rows
        float s0 = 0.f, s1 = 0.f, s2 = 0.f, s3 = 0.f;
        STEP( 0,  0,  1,  2,  3)  STEP( 1,  4,  5,  6,  7)
        STEP( 2,  8,  9, 10, 11)  STEP( 3, 12, 13, 14, 15)
        STEP( 4, 16, 17, 18, 19)  STEP( 5, 20, 21, 22, 23)
        STEP( 6, 24, 25, 26, 27)  STEP( 7, 28, 29, 30, 31)
        STEP( 8, 32, 33, 34, 35)  STEP( 9, 36, 37, 38, 39)
        STEP(10, 40, 41, 42, 43)  STEP(11, 44, 45, 46, 47)
        STEP(12, 48, 49, 50, 51)  STEP(13, 52, 53, 54, 55)
        STEP(14, 56, 57, 58, 59)  STEP(15, 60, 61, 62, 63)
        STEP(16, 64, 65, 66, 67)  STEP(17, 68, 69, 70, 71)
        STEP(18, 72, 73, 74, 75)  STEP(19, 76, 77, 78, 79)
        STEP(20, 80, 81, 82, 83)  STEP(21, 84, 85, 86, 87)
        STEP(22, 88, 89, 90, 91)  STEP(23, 92, 93, 94, 95)
        float s = (s0 + s1) + (s2 + s3);
        if (s > best) {
            second = best;
            best = s;
            bestk = k;
        } else if (s > second) {
            second = s;
        }
    }

    // fast-pass noise < ~5e-6*||x||, numpy noise ~1e-6*||x||; 30x margin.
    float tau = 3e-4f * sqrtf(n2);
    out[g] = (best - second < tau) ? (bestk | (int)0x80000000) : bestk;
}

// ---------------------------------------------------------------------------
// Refine pass (unchanged from round 3): bit-exact numpy-fp32 emulation of
// flagged positions. Thread t handles prototypes t and t+256; LDS tree
// argmax with first-index tie-break.
// ---------------------------------------------------------------------------
__global__ __launch_bounds__(256) void refine_kernel(
        const float* __restrict__ x,
        const float* __restrict__ pn,
        int* __restrict__ out) {
    __shared__ int list[256];
    __shared__ int cnt;
    __shared__ float xn[C];
    __shared__ float nrm_s;
    __shared__ float sc[256];
    __shared__ int ki[256];

    int tid = threadIdx.x;
    int g = blockIdx.x * 256 + tid;

    if (tid == 0) cnt = 0;
    __syncthreads();

    if (out[g] < 0) {
        int i = atomicAdd(&cnt, 1);
        list[i] = g;
    }
    __syncthreads();
    int n = cnt;

    for (int i = 0; i < n; ++i) {
        int gg = list[i];
        int b = (gg >= P_PER_B) ? 1 : 0;
        int p = gg - b * P_PER_B;
        const float* xb = x + (size_t)b * (size_t)C * P_PER_B + p;

        if (tid < C) xn[tid] = xb[(size_t)tid * P_PER_B];
        __syncthreads();

        // numpy: norm over non-contiguous axis -> strictly sequential fp32
        if (tid == 0) {
            float acc = __fmul_rn(xn[0], xn[0]);
            for (int c = 1; c < C; ++c)
                acc = __fadd_rn(acc, __fmul_rn(xn[c], xn[c]));
            nrm_s = fmaxf(__fsqrt_rn(acc), 1e-12f);
        }
        __syncthreads();
        if (tid < C) xn[tid] = __fdiv_rn(xn[tid], nrm_s);
        __syncthreads();

        // einsum optimize=False: sequential fp32 mul+add, c ascending, no FMA
        const float* pr0 = pn + (size_t)tid * C;
        const float* pr1 = pn + (size_t)(tid + 256) * C;
        float s0 = 0.f, s1 = 0.f;
        for (int c = 0; c < C; ++c) {
            s0 = __fadd_rn(s0, __fmul_rn(xn[c], pr0[c]));
            s1 = __fadd_rn(s1, __fmul_rn(xn[c], pr1[c]));
        }

        float bv = s0;
        int bk = tid;
        if (s1 > bv) { bv = s1; bk = tid + 256; }  // strict: lower index wins ties

        sc[tid] = bv;
        ki[tid] = bk;
        __syncthreads();

        for (int off = 128; off > 0; off >>= 1) {
            if (tid < off) {
                float ov = sc[tid + off];
                int oi = ki[tid + off];
                if (ov > sc[tid] || (ov == sc[tid] && oi < ki[tid])) {
                    sc[tid] = ov;
                    ki[tid] = oi;
                }
            }
            __syncthreads();
        }

        if (tid == 0) out[gg] = ki[0];
        __syncthreads();
    }
}

// ---------------------------------------------------------------------------
extern "C" void kernel_launch(void* const* d_in, const int* in_sizes, int n_in,
                              void* d_out, int out_size, void* d_ws, size_t ws_size,
                              hipStream_t stream) {
    const float* x = (const float*)d_in[0];      // [2,96,48,48,48] fp32
    const float* proto = (const float*)d_in[1];  // [512,96] fp32
    int* out = (int*)d_out;                      // [2,48,48,48] int32

    float* pn = (float*)d_ws;                    // 512*96*4 = 196608 B

    prep_kernel<<<2, 256, 0, stream>>>(proto, pn);
    sim_argmax_kernel<<<NPOS / 256, 256, 0, stream>>>(x, pn, out);
    refine_kernel<<<NPOS / 256, 256, 0, stream>>>(x, pn, out);
}